// Round 19
// baseline (117.963 us; speedup 1.0000x reference)
//
#include <hip/hip_runtime.h>
#include <hip/hip_bf16.h>
#include <cstdint>
#include <cstddef>

#define NSRC 100000
#define NDST 50000
#define DOUT 128
#define KK2 256    // 2*D
#define NBUCK 196  // ceil(NDST/256) buckets of 256 dst each
#define CHUNK 4096 // edges per block in binning passes

typedef __attribute__((ext_vector_type(8))) short bf16x8;
typedef __attribute__((ext_vector_type(4))) float f32x4;
typedef __attribute__((ext_vector_type(2))) float f32x2;

static __device__ __forceinline__ unsigned short f2bf(float f) {
    union { float f; uint32_t u; } v; v.f = f;
    uint32_t u = v.u;
    uint32_t r = u + 0x7FFFu + ((u >> 16) & 1u);   // round-to-nearest-even
    return (unsigned short)(r >> 16);
}

// ---------------- K1: role-split: dst histogram | WT convert | fp8 encode ----------------
// blocks [0, nbe): LDS-aggregated 196-bucket histogram of dst
// blocks [nbe, nbe+128): WT bf16 convert
// blocks [nbe+128, ...): hdelta fp8 encode, ONE float4 per thread (dense)
__global__ __launch_bounds__(256) void k_hd_binA1(const float4* __restrict__ a,
                                                  const float4* __restrict__ b,
                                                  uint32_t* __restrict__ o, int n4,
                                                  const int* __restrict__ dst,
                                                  int* __restrict__ bcnt,
                                                  const float* __restrict__ W,
                                                  unsigned short* __restrict__ WT,
                                                  int E, int nbe) {
    __shared__ int bh[NBUCK];
    int t = threadIdx.x;
    int bid = blockIdx.x;
    if (bid < nbe) {
        if (t < NBUCK) bh[t] = 0;
        __syncthreads();
        int base = bid * CHUNK;
        for (int i = t; i < CHUNK; i += 256) {
            int e = base + i;
            if (e < E) atomicAdd(&bh[dst[e] >> 8], 1);
        }
        __syncthreads();
        if (t < NBUCK && bh[t]) atomicAdd(&bcnt[t], bh[t]);
    } else if (bid < nbe + 128) {
        int i = (bid - nbe) * 256 + t;   // < 32768
        int n = i >> 8, k = i & 255;
        WT[i] = f2bf(W[k * DOUT + n]);
    } else {
        int i = (bid - nbe - 128) * 256 + t;
        if (i < n4) {
            float4 x = a[i], y = b[i];
            uint32_t p = __builtin_amdgcn_cvt_pk_fp8_f32(x.x - y.x, x.y - y.y, 0u, false);
            p = __builtin_amdgcn_cvt_pk_fp8_f32(x.z - y.z, x.w - y.w, p, true);
            o[i] = p;
        }
    }
}

// ---------------- K2: bin edges into bucket regions (atomic bucket cursors) ----------------
__global__ __launch_bounds__(256) void k_binA2(const int* __restrict__ src,
                                               const int* __restrict__ dst,
                                               const int* __restrict__ bcnt,
                                               int* __restrict__ bcur2,
                                               uint32_t* __restrict__ pairs, int E) {
    __shared__ int bh[NBUCK], lcur[NBUCK];
    __shared__ int wsum[4], wex[4];
    int t = threadIdx.x;
    int lane = t & 63, w = t >> 6;

    if (t < NBUCK) bh[t] = 0;
    __syncthreads();
    int base = blockIdx.x * CHUNK;
    for (int i = t; i < CHUNK; i += 256) {
        int e = base + i;
        if (e < E) atomicAdd(&bh[dst[e] >> 8], 1);
    }

    // in-block exclusive scan of bcnt -> bucket base
    int v = (t < NBUCK) ? bcnt[t] : 0;
    int x = v;
#pragma unroll
    for (int s = 1; s < 64; s <<= 1) { int tt = __shfl_up(x, s, 64); if (lane >= s) x += tt; }
    if (lane == 63) wsum[w] = x;
    __syncthreads();
    if (t == 0) {
        int run = 0;
#pragma unroll
        for (int k = 0; k < 4; ++k) { wex[k] = run; run += wsum[k]; }
    }
    __syncthreads();
    int ex = wex[w] + x - v;

    if (t < NBUCK) lcur[t] = bh[t] ? (ex + atomicAdd(&bcur2[t], bh[t])) : 0;
    __syncthreads();

    for (int i = t; i < CHUNK; i += 256) {
        int e = base + i;
        if (e < E) {
            int d = dst[e];
            int pos = atomicAdd(&lcur[d >> 8], 1);
            pairs[pos] = ((uint32_t)(d & 255) << 24) | (uint32_t)src[e];
        }
    }
}

// ---------------- K3: per-bucket local sort: off[] + idx[] ----------------
__global__ __launch_bounds__(256) void k_binB(const uint32_t* __restrict__ pairs,
                                              const int* __restrict__ bcnt,
                                              int* __restrict__ off,
                                              int* __restrict__ idx, int E) {
    __shared__ int lcnt[256];
    __shared__ int lcur[256];
    __shared__ int wsum[4], wex[4];
    __shared__ int gbase_s;
    int b = blockIdx.x, t = threadIdx.x;
    int lane = t & 63, w = t >> 6;

    // in-block exclusive scan of bcnt -> this bucket's base
    int v = (t < NBUCK) ? bcnt[t] : 0;
    int x = v;
#pragma unroll
    for (int s = 1; s < 64; s <<= 1) { int tt = __shfl_up(x, s, 64); if (lane >= s) x += tt; }
    if (lane == 63) wsum[w] = x;
    __syncthreads();
    if (t == 0) {
        int run = 0;
#pragma unroll
        for (int k = 0; k < 4; ++k) { wex[k] = run; run += wsum[k]; }
    }
    __syncthreads();
    if (t == b) gbase_s = wex[w] + x - v;
    lcnt[t] = 0;
    __syncthreads();
    int gbase = gbase_s;
    int cnt = bcnt[b];

    for (int i = t; i < cnt; i += 256)
        atomicAdd(&lcnt[pairs[gbase + i] >> 24], 1);
    __syncthreads();

    // block-wide exclusive scan of lcnt
    v = lcnt[t];
    x = v;
#pragma unroll
    for (int s = 1; s < 64; s <<= 1) { int tt = __shfl_up(x, s, 64); if (lane >= s) x += tt; }
    if (lane == 63) wsum[w] = x;
    __syncthreads();
    if (t == 0) {
        int run = 0;
#pragma unroll
        for (int k = 0; k < 4; ++k) { wex[k] = run; run += wsum[k]; }
    }
    __syncthreads();
    int ex = wex[w] + x - v;
    lcur[t] = ex;
    int d = b * 256 + t;
    if (d < NDST) off[d] = gbase + ex;
    if (b == 0 && t == 0) off[NDST] = E;
    __syncthreads();

    for (int i = t; i < cnt; i += 256) {
        uint32_t p = pairs[gbase + i];
        int pos = atomicAdd(&lcur[p >> 24], 1);
        idx[gbase + pos] = (int)(p & 0xFFFFFFu);
    }
}

// ---------------- K4: barrier-free gather-mean-agg -> Xn (half-wave, masked unroll) ----------------
// 4 waves/block, ONE dst row per wave. Half-wave gathers: lane owns 4 cols
// (uint = 4 fp8); two halves gather 2 edges/round; masked full-unroll x8 —
// 16 edges (8 loads) per round always issue, OOB edges masked to 0.
__global__ __launch_bounds__(256) void k_gath(const uint32_t* __restrict__ hd8u,
                                              const float4* __restrict__ agg4,
                                              const int* __restrict__ off,
                                              const int* __restrict__ idx,
                                              ushort4* __restrict__ Xn, int n) {
    int r = blockIdx.x * 4 + (threadIdx.x >> 6);
    if (r >= n) return;
    int lane = threadIdx.x & 63;
    int li = lane & 31, half = lane >> 5;
    float a0 = 0.f, a1 = 0.f, a2 = 0.f, a3 = 0.f;
    int o0 = off[r], o1 = off[r + 1];
    for (int c = o0; c < o1; c += 64) {
        int m = o1 - c; if (m > 64) m = 64;
        int myi = (lane < m) ? idx[c + lane] : 0;
        for (int j = 0; j < m; j += 16) {
            int t0 = j + 0 + half,  t1 = j + 2 + half,  t2 = j + 4 + half,  t3 = j + 6 + half;
            int t4 = j + 8 + half,  t5 = j + 10 + half, t6 = j + 12 + half, t7 = j + 14 + half;
            int s0 = __shfl(myi, t0), s1 = __shfl(myi, t1);
            int s2 = __shfl(myi, t2), s3 = __shfl(myi, t3);
            int s4 = __shfl(myi, t4), s5 = __shfl(myi, t5);
            int s6 = __shfl(myi, t6), s7 = __shfl(myi, t7);
            uint32_t u0 = hd8u[(size_t)s0 * 32 + li];
            uint32_t u1 = hd8u[(size_t)s1 * 32 + li];
            uint32_t u2 = hd8u[(size_t)s2 * 32 + li];
            uint32_t u3 = hd8u[(size_t)s3 * 32 + li];
            uint32_t u4 = hd8u[(size_t)s4 * 32 + li];
            uint32_t u5 = hd8u[(size_t)s5 * 32 + li];
            uint32_t u6 = hd8u[(size_t)s6 * 32 + li];
            uint32_t u7 = hd8u[(size_t)s7 * 32 + li];
            if (t0 >= m) u0 = 0;  if (t1 >= m) u1 = 0;
            if (t2 >= m) u2 = 0;  if (t3 >= m) u3 = 0;
            if (t4 >= m) u4 = 0;  if (t5 >= m) u5 = 0;
            if (t6 >= m) u6 = 0;  if (t7 >= m) u7 = 0;
            f32x2 l0 = __builtin_amdgcn_cvt_pk_f32_fp8(u0, false);
            f32x2 h0 = __builtin_amdgcn_cvt_pk_f32_fp8(u0, true);
            f32x2 l1 = __builtin_amdgcn_cvt_pk_f32_fp8(u1, false);
            f32x2 h1 = __builtin_amdgcn_cvt_pk_f32_fp8(u1, true);
            f32x2 l2 = __builtin_amdgcn_cvt_pk_f32_fp8(u2, false);
            f32x2 h2 = __builtin_amdgcn_cvt_pk_f32_fp8(u2, true);
            f32x2 l3 = __builtin_amdgcn_cvt_pk_f32_fp8(u3, false);
            f32x2 h3 = __builtin_amdgcn_cvt_pk_f32_fp8(u3, true);
            f32x2 l4 = __builtin_amdgcn_cvt_pk_f32_fp8(u4, false);
            f32x2 h4 = __builtin_amdgcn_cvt_pk_f32_fp8(u4, true);
            f32x2 l5 = __builtin_amdgcn_cvt_pk_f32_fp8(u5, false);
            f32x2 h5 = __builtin_amdgcn_cvt_pk_f32_fp8(u5, true);
            f32x2 l6 = __builtin_amdgcn_cvt_pk_f32_fp8(u6, false);
            f32x2 h6 = __builtin_amdgcn_cvt_pk_f32_fp8(u6, true);
            f32x2 l7 = __builtin_amdgcn_cvt_pk_f32_fp8(u7, false);
            f32x2 h7 = __builtin_amdgcn_cvt_pk_f32_fp8(u7, true);
            a0 += l0[0] + l1[0] + l2[0] + l3[0] + l4[0] + l5[0] + l6[0] + l7[0];
            a1 += l0[1] + l1[1] + l2[1] + l3[1] + l4[1] + l5[1] + l6[1] + l7[1];
            a2 += h0[0] + h1[0] + h2[0] + h3[0] + h4[0] + h5[0] + h6[0] + h7[0];
            a3 += h0[1] + h1[1] + h2[1] + h3[1] + h4[1] + h5[1] + h6[1] + h7[1];
        }
    }
    // combine the two halves
    a0 += __shfl_xor(a0, 32); a1 += __shfl_xor(a1, 32);
    a2 += __shfl_xor(a2, 32); a3 += __shfl_xor(a3, 32);
    if (half == 0) {
        float inv = 1.0f / fmaxf((float)(o1 - o0), 1.0f);
        float4 g = agg4[(size_t)r * 32 + li];
        ushort4 u;
        u.x = f2bf(g.x + a0 * inv); u.y = f2bf(g.y + a1 * inv);
        u.z = f2bf(g.z + a2 * inv); u.w = f2bf(g.w + a3 * inv);
        Xn[(size_t)r * 32 + li] = u;
    }
}

// ---------------- K5: GEMM [NDST,256] x [256,128] + bias + relu, LDS-staged A ----------------
__global__ __launch_bounds__(256) void k_gemm(const float4* __restrict__ Hd4,
                                              const unsigned short* __restrict__ Xn,
                                              const unsigned short* __restrict__ WT,
                                              const float* __restrict__ bias,
                                              float* __restrict__ out) {
    __shared__ __align__(16) unsigned short xt[16][264];
    int r0 = blockIdx.x * 16;
    int t = threadIdx.x;

    // ---- stage A-tile (dense loads) ----
    {
#pragma unroll
        for (int p = 0; p < 2; ++p) {
            int f = t + p * 256;
            int row = f >> 5, c4 = f & 31;
            float4 v = Hd4[(size_t)(r0 + row) * 32 + c4];
            ushort4 u;
            u.x = f2bf(v.x); u.y = f2bf(v.y); u.z = f2bf(v.z); u.w = f2bf(v.w);
            *(ushort4*)&xt[row][c4 * 4] = u;
        }
        int row = t >> 4, col8 = (t & 15) * 8;
        bf16x8 xv = *reinterpret_cast<const bf16x8*>(Xn + (size_t)(r0 + row) * 128 + col8);
        *(bf16x8*)&xt[row][128 + col8] = xv;
    }
    __syncthreads();

    // ---- MFMA phase ----
    int w = t >> 6, lane = t & 63;
    int lr = lane & 15, lg = lane >> 4;
    const bf16x8* B0 = reinterpret_cast<const bf16x8*>(WT + (size_t)(w * 32 + lr) * KK2 + lg * 8);
    const bf16x8* B1 = reinterpret_cast<const bf16x8*>(WT + (size_t)(w * 32 + 16 + lr) * KK2 + lg * 8);

    f32x4 acc0 = {0.f, 0.f, 0.f, 0.f};
    f32x4 acc1 = {0.f, 0.f, 0.f, 0.f};
#pragma unroll
    for (int kk = 0; kk < 8; ++kk) {
        bf16x8 av = *reinterpret_cast<const bf16x8*>(&xt[lr][lg * 8 + kk * 32]);
        acc0 = __builtin_amdgcn_mfma_f32_16x16x32_bf16(av, B0[kk * 4], acc0, 0, 0, 0);
        acc1 = __builtin_amdgcn_mfma_f32_16x16x32_bf16(av, B1[kk * 4], acc1, 0, 0, 0);
    }

    int col0 = w * 32 + lr;
    int col1 = col0 + 16;
    float bi0 = bias[col0], bi1 = bias[col1];
    int rowb = r0 + lg * 4;
#pragma unroll
    for (int j = 0; j < 4; ++j) {
        float v0 = acc0[j] + bi0;
        float v1 = acc1[j] + bi1;
        out[(size_t)(rowb + j) * DOUT + col0] = v0 > 0.f ? v0 : 0.f;
        out[(size_t)(rowb + j) * DOUT + col1] = v1 > 0.f ? v1 : 0.f;
    }
}

extern "C" void kernel_launch(void* const* d_in, const int* in_sizes, int n_in,
                              void* d_out, int out_size, void* d_ws, size_t ws_size,
                              hipStream_t stream) {
    const float* H_src    = (const float*)d_in[0];
    const float* H_dst    = (const float*)d_in[1];
    const float* HBar_src = (const float*)d_in[2];
    const float* agg      = (const float*)d_in[3];
    const float* W        = (const float*)d_in[4];
    const float* bias     = (const float*)d_in[5];
    const int*   src      = (const int*)d_in[6];
    const int*   dst      = (const int*)d_in[7];
    float* out = (float*)d_out;
    const int E = in_sizes[6];

    // ws layout (byte offsets):
    //   bcnt   : 0          .. 1,024      (256 i32, zeroed by memset)
    //   bcur2  : 1,024      .. 2,048      (256 i32, zeroed by memset)
    //   off    : 3,072      .. 203,076    (NDST+1 i32)
    //   pairs  : 203,264    .. 3,403,264  (E u32)
    //   idx    : 3,403,264  .. 6,603,264  (E i32)
    //   WT     : 6,603,264  .. 6,668,800  (128*256 bf16)
    //   hd8    : 6,668,800  .. 19,468,800 (NSRC*128 fp8)
    //   Xn     : 19,468,800 .. 32,268,800 (NDST*128 bf16)
    char* ws = (char*)d_ws;
    int* bcnt            = (int*)ws;
    int* bcur2           = (int*)(ws + 1024);
    int* off             = (int*)(ws + 3072);
    uint32_t* pairs      = (uint32_t*)(ws + 203264);
    int* idx_sorted      = (int*)(ws + 3403264);
    unsigned short* WT   = (unsigned short*)(ws + 6603264);
    unsigned short* hd8  = (unsigned short*)(ws + 6668800);
    unsigned short* Xn   = (unsigned short*)(ws + 19468800);

    const int NBE = (E + CHUNK - 1) / CHUNK;   // 196 binning blocks
    int n4 = NSRC * 32;                        // float4 count (one per thread)
    int nStream = (n4 + 255) / 256;            // 12500

    hipMemsetAsync(ws, 0, 2048, stream);       // bcnt + bcur2

    k_hd_binA1<<<NBE + 128 + nStream, 256, 0, stream>>>(
        (const float4*)H_src, (const float4*)HBar_src, (uint32_t*)hd8, n4,
        dst, bcnt, W, WT, E, NBE);

    k_binA2<<<NBE, 256, 0, stream>>>(src, dst, bcnt, bcur2, pairs, E);
    k_binB<<<NBUCK, 256, 0, stream>>>(pairs, bcnt, off, idx_sorted, E);

    k_gath<<<(NDST + 3) / 4, 256, 0, stream>>>(
        (const uint32_t*)hd8, (const float4*)agg, off, idx_sorted,
        (ushort4*)Xn, NDST);

    k_gemm<<<NDST / 16, 256, 0, stream>>>(
        (const float4*)H_dst, Xn, WT, bias, out);
}

// Round 20
// 113.305 us; speedup vs baseline: 1.0411x; 1.0411x over previous
//
#include <hip/hip_runtime.h>
#include <hip/hip_bf16.h>
#include <cstdint>
#include <cstddef>

#define NSRC 100000
#define NDST 50000
#define DOUT 128
#define KK2 256    // 2*D
#define NBUCK 196  // ceil(NDST/256) buckets of 256 dst each
#define CHUNK 4096 // edges per block in binning passes

typedef __attribute__((ext_vector_type(8))) short bf16x8;
typedef __attribute__((ext_vector_type(4))) float f32x4;
typedef __attribute__((ext_vector_type(2))) float f32x2;

static __device__ __forceinline__ unsigned short f2bf(float f) {
    union { float f; uint32_t u; } v; v.f = f;
    uint32_t u = v.u;
    uint32_t r = u + 0x7FFFu + ((u >> 16) & 1u);   // round-to-nearest-even
    return (unsigned short)(r >> 16);
}

// ---------------- K1: prep — WT bf16 convert + zero bucket counters ----------------
__global__ __launch_bounds__(256) void k_prep(const float* __restrict__ W,
                                              unsigned short* __restrict__ WT,
                                              int* __restrict__ bcnt,
                                              int* __restrict__ bcur2) {
    int i = blockIdx.x * 256 + threadIdx.x;
    if (i < DOUT * KK2) {
        int n = i >> 8;    // output col
        int k = i & 255;   // k index
        WT[i] = f2bf(W[k * DOUT + n]);
    }
    if (i < 256) { bcnt[i] = 0; bcur2[i] = 0; }
}

// ---------------- K2: fused hdelta_fp8 stream + bucket histogram (role-split) ----------------
// blocks [0, NBE): LDS-aggregated 196-bucket histogram of dst
// blocks [NBE, ...): fp8 encode stream, ONE float4 per thread (fully dense loads/stores)
__global__ __launch_bounds__(256) void k_hd_binA1(const float4* __restrict__ a,
                                                  const float4* __restrict__ b,
                                                  uint32_t* __restrict__ o, int n4,
                                                  const int* __restrict__ dst,
                                                  int* __restrict__ bcnt,
                                                  int E, int nbe) {
    __shared__ int bh[NBUCK];
    int t = threadIdx.x;
    if ((int)blockIdx.x < nbe) {
        if (t < NBUCK) bh[t] = 0;
        __syncthreads();
        int base = blockIdx.x * CHUNK;
        for (int i = t; i < CHUNK; i += 256) {
            int e = base + i;
            if (e < E) atomicAdd(&bh[dst[e] >> 8], 1);
        }
        __syncthreads();
        if (t < NBUCK && bh[t]) atomicAdd(&bcnt[t], bh[t]);
    } else {
        int i = ((int)blockIdx.x - nbe) * 256 + t;
        if (i < n4) {
            float4 x = a[i], y = b[i];
            uint32_t p = __builtin_amdgcn_cvt_pk_fp8_f32(x.x - y.x, x.y - y.y, 0u, false);
            p = __builtin_amdgcn_cvt_pk_fp8_f32(x.z - y.z, x.w - y.w, p, true);
            o[i] = p;
        }
    }
}

// ---------------- K3: bin edges into bucket regions (atomic bucket cursors) ----------------
__global__ __launch_bounds__(256) void k_binA2(const int* __restrict__ src,
                                               const int* __restrict__ dst,
                                               const int* __restrict__ bcnt,
                                               int* __restrict__ bcur2,
                                               uint32_t* __restrict__ pairs, int E) {
    __shared__ int bh[NBUCK], lcur[NBUCK];
    __shared__ int wsum[4], wex[4];
    int t = threadIdx.x;
    int lane = t & 63, w = t >> 6;

    if (t < NBUCK) bh[t] = 0;
    __syncthreads();
    int base = blockIdx.x * CHUNK;
    for (int i = t; i < CHUNK; i += 256) {
        int e = base + i;
        if (e < E) atomicAdd(&bh[dst[e] >> 8], 1);
    }

    // in-block exclusive scan of bcnt -> bucket base
    int v = (t < NBUCK) ? bcnt[t] : 0;
    int x = v;
#pragma unroll
    for (int s = 1; s < 64; s <<= 1) { int tt = __shfl_up(x, s, 64); if (lane >= s) x += tt; }
    if (lane == 63) wsum[w] = x;
    __syncthreads();
    if (t == 0) {
        int run = 0;
#pragma unroll
        for (int k = 0; k < 4; ++k) { wex[k] = run; run += wsum[k]; }
    }
    __syncthreads();
    int ex = wex[w] + x - v;

    if (t < NBUCK) lcur[t] = bh[t] ? (ex + atomicAdd(&bcur2[t], bh[t])) : 0;
    __syncthreads();

    for (int i = t; i < CHUNK; i += 256) {
        int e = base + i;
        if (e < E) {
            int d = dst[e];
            int pos = atomicAdd(&lcur[d >> 8], 1);
            pairs[pos] = ((uint32_t)(d & 255) << 24) | (uint32_t)src[e];
        }
    }
}

// ---------------- K4: per-bucket local sort: off[] + idx[] ----------------
__global__ __launch_bounds__(256) void k_binB(const uint32_t* __restrict__ pairs,
                                              const int* __restrict__ bcnt,
                                              int* __restrict__ off,
                                              int* __restrict__ idx, int E) {
    __shared__ int lcnt[256];
    __shared__ int lcur[256];
    __shared__ int wsum[4], wex[4];
    __shared__ int gbase_s;
    int b = blockIdx.x, t = threadIdx.x;
    int lane = t & 63, w = t >> 6;

    // in-block exclusive scan of bcnt -> this bucket's base
    int v = (t < NBUCK) ? bcnt[t] : 0;
    int x = v;
#pragma unroll
    for (int s = 1; s < 64; s <<= 1) { int tt = __shfl_up(x, s, 64); if (lane >= s) x += tt; }
    if (lane == 63) wsum[w] = x;
    __syncthreads();
    if (t == 0) {
        int run = 0;
#pragma unroll
        for (int k = 0; k < 4; ++k) { wex[k] = run; run += wsum[k]; }
    }
    __syncthreads();
    if (t == b) gbase_s = wex[w] + x - v;
    lcnt[t] = 0;
    __syncthreads();
    int gbase = gbase_s;
    int cnt = bcnt[b];

    for (int i = t; i < cnt; i += 256)
        atomicAdd(&lcnt[pairs[gbase + i] >> 24], 1);
    __syncthreads();

    // block-wide exclusive scan of lcnt
    v = lcnt[t];
    x = v;
#pragma unroll
    for (int s = 1; s < 64; s <<= 1) { int tt = __shfl_up(x, s, 64); if (lane >= s) x += tt; }
    if (lane == 63) wsum[w] = x;
    __syncthreads();
    if (t == 0) {
        int run = 0;
#pragma unroll
        for (int k = 0; k < 4; ++k) { wex[k] = run; run += wsum[k]; }
    }
    __syncthreads();
    int ex = wex[w] + x - v;
    lcur[t] = ex;
    int d = b * 256 + t;
    if (d < NDST) off[d] = gbase + ex;
    if (b == 0 && t == 0) off[NDST] = E;
    __syncthreads();

    for (int i = t; i < cnt; i += 256) {
        uint32_t p = pairs[gbase + i];
        int pos = atomicAdd(&lcur[p >> 24], 1);
        idx[gbase + pos] = (int)(p & 0xFFFFFFu);
    }
}

// ---------------- K5: barrier-free gather-mean-agg -> Xn (h_neigh, bf16) ----------------
// 4 waves/block, ONE dst row per wave, no barrier. Half-wave gathers: lane owns
// 4 cols (uint = 4 fp8); two halves gather 2 edges/round; MASKED FULL-UNROLL —
// 16 edges (8 loads) per round always issue, OOB edges masked to 0 (shfl of
// lane>=m yields 0 -> row-0 load, L1-hot, result zeroed). No serial tail.
__global__ __launch_bounds__(256) void k_gath(const uint32_t* __restrict__ hd8u,
                                              const float4* __restrict__ agg4,
                                              const int* __restrict__ off,
                                              const int* __restrict__ idx,
                                              ushort4* __restrict__ Xn, int n) {
    int r = blockIdx.x * 4 + (threadIdx.x >> 6);
    if (r >= n) return;
    int lane = threadIdx.x & 63;
    int li = lane & 31, half = lane >> 5;
    float a0 = 0.f, a1 = 0.f, a2 = 0.f, a3 = 0.f;
    int o0 = off[r], o1 = off[r + 1];
    for (int c = o0; c < o1; c += 64) {
        int m = o1 - c; if (m > 64) m = 64;
        int myi = (lane < m) ? idx[c + lane] : 0;
        for (int j = 0; j < m; j += 16) {
            int t0 = j + 0 + half,  t1 = j + 2 + half,  t2 = j + 4 + half,  t3 = j + 6 + half;
            int t4 = j + 8 + half,  t5 = j + 10 + half, t6 = j + 12 + half, t7 = j + 14 + half;
            int s0 = __shfl(myi, t0), s1 = __shfl(myi, t1);
            int s2 = __shfl(myi, t2), s3 = __shfl(myi, t3);
            int s4 = __shfl(myi, t4), s5 = __shfl(myi, t5);
            int s6 = __shfl(myi, t6), s7 = __shfl(myi, t7);
            uint32_t u0 = hd8u[(size_t)s0 * 32 + li];
            uint32_t u1 = hd8u[(size_t)s1 * 32 + li];
            uint32_t u2 = hd8u[(size_t)s2 * 32 + li];
            uint32_t u3 = hd8u[(size_t)s3 * 32 + li];
            uint32_t u4 = hd8u[(size_t)s4 * 32 + li];
            uint32_t u5 = hd8u[(size_t)s5 * 32 + li];
            uint32_t u6 = hd8u[(size_t)s6 * 32 + li];
            uint32_t u7 = hd8u[(size_t)s7 * 32 + li];
            if (t0 >= m) u0 = 0;  if (t1 >= m) u1 = 0;
            if (t2 >= m) u2 = 0;  if (t3 >= m) u3 = 0;
            if (t4 >= m) u4 = 0;  if (t5 >= m) u5 = 0;
            if (t6 >= m) u6 = 0;  if (t7 >= m) u7 = 0;
            f32x2 l0 = __builtin_amdgcn_cvt_pk_f32_fp8(u0, false);
            f32x2 h0 = __builtin_amdgcn_cvt_pk_f32_fp8(u0, true);
            f32x2 l1 = __builtin_amdgcn_cvt_pk_f32_fp8(u1, false);
            f32x2 h1 = __builtin_amdgcn_cvt_pk_f32_fp8(u1, true);
            f32x2 l2 = __builtin_amdgcn_cvt_pk_f32_fp8(u2, false);
            f32x2 h2 = __builtin_amdgcn_cvt_pk_f32_fp8(u2, true);
            f32x2 l3 = __builtin_amdgcn_cvt_pk_f32_fp8(u3, false);
            f32x2 h3 = __builtin_amdgcn_cvt_pk_f32_fp8(u3, true);
            f32x2 l4 = __builtin_amdgcn_cvt_pk_f32_fp8(u4, false);
            f32x2 h4 = __builtin_amdgcn_cvt_pk_f32_fp8(u4, true);
            f32x2 l5 = __builtin_amdgcn_cvt_pk_f32_fp8(u5, false);
            f32x2 h5 = __builtin_amdgcn_cvt_pk_f32_fp8(u5, true);
            f32x2 l6 = __builtin_amdgcn_cvt_pk_f32_fp8(u6, false);
            f32x2 h6 = __builtin_amdgcn_cvt_pk_f32_fp8(u6, true);
            f32x2 l7 = __builtin_amdgcn_cvt_pk_f32_fp8(u7, false);
            f32x2 h7 = __builtin_amdgcn_cvt_pk_f32_fp8(u7, true);
            a0 += l0[0] + l1[0] + l2[0] + l3[0] + l4[0] + l5[0] + l6[0] + l7[0];
            a1 += l0[1] + l1[1] + l2[1] + l3[1] + l4[1] + l5[1] + l6[1] + l7[1];
            a2 += h0[0] + h1[0] + h2[0] + h3[0] + h4[0] + h5[0] + h6[0] + h7[0];
            a3 += h0[1] + h1[1] + h2[1] + h3[1] + h4[1] + h5[1] + h6[1] + h7[1];
        }
    }
    // combine the two halves
    a0 += __shfl_xor(a0, 32); a1 += __shfl_xor(a1, 32);
    a2 += __shfl_xor(a2, 32); a3 += __shfl_xor(a3, 32);
    if (half == 0) {
        float inv = 1.0f / fmaxf((float)(o1 - o0), 1.0f);
        float4 g = agg4[(size_t)r * 32 + li];
        ushort4 u;
        u.x = f2bf(g.x + a0 * inv); u.y = f2bf(g.y + a1 * inv);
        u.z = f2bf(g.z + a2 * inv); u.w = f2bf(g.w + a3 * inv);
        Xn[(size_t)r * 32 + li] = u;
    }
}

// ---------------- K6: GEMM [NDST,256] x [256,128] + bias + relu, LDS-staged A ----------------
__global__ __launch_bounds__(256) void k_gemm(const float4* __restrict__ Hd4,
                                              const unsigned short* __restrict__ Xn,
                                              const unsigned short* __restrict__ WT,
                                              const float* __restrict__ bias,
                                              float* __restrict__ out) {
    __shared__ __align__(16) unsigned short xt[16][264];
    int r0 = blockIdx.x * 16;
    int t = threadIdx.x;

    // ---- stage A-tile (dense loads) ----
    {
        // H_dst half: tile = 16 rows x 32 float4; thread t takes flat f4 #t and #(t+256)
#pragma unroll
        for (int p = 0; p < 2; ++p) {
            int f = t + p * 256;
            int row = f >> 5, c4 = f & 31;
            float4 v = Hd4[(size_t)(r0 + row) * 32 + c4];
            ushort4 u;
            u.x = f2bf(v.x); u.y = f2bf(v.y); u.z = f2bf(v.z); u.w = f2bf(v.w);
            *(ushort4*)&xt[row][c4 * 4] = u;
        }
        // Xn half: 16 rows x 128 bf16; thread t takes 8 bf16 (dense 16B)
        int row = t >> 4, col8 = (t & 15) * 8;
        bf16x8 xv = *reinterpret_cast<const bf16x8*>(Xn + (size_t)(r0 + row) * 128 + col8);
        *(bf16x8*)&xt[row][128 + col8] = xv;
    }
    __syncthreads();

    // ---- MFMA phase ----
    int w = t >> 6, lane = t & 63;
    int lr = lane & 15, lg = lane >> 4;
    const bf16x8* B0 = reinterpret_cast<const bf16x8*>(WT + (size_t)(w * 32 + lr) * KK2 + lg * 8);
    const bf16x8* B1 = reinterpret_cast<const bf16x8*>(WT + (size_t)(w * 32 + 16 + lr) * KK2 + lg * 8);

    f32x4 acc0 = {0.f, 0.f, 0.f, 0.f};
    f32x4 acc1 = {0.f, 0.f, 0.f, 0.f};
#pragma unroll
    for (int kk = 0; kk < 8; ++kk) {
        bf16x8 av = *reinterpret_cast<const bf16x8*>(&xt[lr][lg * 8 + kk * 32]);
        acc0 = __builtin_amdgcn_mfma_f32_16x16x32_bf16(av, B0[kk * 4], acc0, 0, 0, 0);
        acc1 = __builtin_amdgcn_mfma_f32_16x16x32_bf16(av, B1[kk * 4], acc1, 0, 0, 0);
    }

    int col0 = w * 32 + lr;
    int col1 = col0 + 16;
    float bi0 = bias[col0], bi1 = bias[col1];
    int rowb = r0 + lg * 4;
#pragma unroll
    for (int j = 0; j < 4; ++j) {
        float v0 = acc0[j] + bi0;
        float v1 = acc1[j] + bi1;
        out[(size_t)(rowb + j) * DOUT + col0] = v0 > 0.f ? v0 : 0.f;
        out[(size_t)(rowb + j) * DOUT + col1] = v1 > 0.f ? v1 : 0.f;
    }
}

extern "C" void kernel_launch(void* const* d_in, const int* in_sizes, int n_in,
                              void* d_out, int out_size, void* d_ws, size_t ws_size,
                              hipStream_t stream) {
    const float* H_src    = (const float*)d_in[0];
    const float* H_dst    = (const float*)d_in[1];
    const float* HBar_src = (const float*)d_in[2];
    const float* agg      = (const float*)d_in[3];
    const float* W        = (const float*)d_in[4];
    const float* bias     = (const float*)d_in[5];
    const int*   src      = (const int*)d_in[6];
    const int*   dst      = (const int*)d_in[7];
    float* out = (float*)d_out;
    const int E = in_sizes[6];

    // ws layout (byte offsets):
    //   bcnt   : 0          .. 1,024      (256 i32, zeroed in prep)
    //   bcur2  : 1,024      .. 2,048
    //   off    : 3,072      .. 203,076    (NDST+1 i32)
    //   pairs  : 203,264    .. 3,403,264  (E u32)
    //   idx    : 3,403,264  .. 6,603,264  (E i32)
    //   WT     : 6,603,264  .. 6,668,800  (128*256 bf16)
    //   hd8    : 6,668,800  .. 19,468,800 (NSRC*128 fp8)
    //   Xn     : 19,468,800 .. 32,268,800 (NDST*128 bf16)
    char* ws = (char*)d_ws;
    int* bcnt            = (int*)ws;
    int* bcur2           = (int*)(ws + 1024);
    int* off             = (int*)(ws + 3072);
    uint32_t* pairs      = (uint32_t*)(ws + 203264);
    int* idx_sorted      = (int*)(ws + 3403264);
    unsigned short* WT   = (unsigned short*)(ws + 6603264);
    unsigned short* hd8  = (unsigned short*)(ws + 6668800);
    unsigned short* Xn   = (unsigned short*)(ws + 19468800);

    const int NBE = (E + CHUNK - 1) / CHUNK;   // 196 binning blocks
    int n4 = NSRC * 32;                        // float4 count (one per thread)
    int nStream = (n4 + 255) / 256;

    k_prep<<<128, 256, 0, stream>>>(W, WT, bcnt, bcur2);

    k_hd_binA1<<<NBE + nStream, 256, 0, stream>>>(
        (const float4*)H_src, (const float4*)HBar_src, (uint32_t*)hd8, n4,
        dst, bcnt, E, NBE);

    k_binA2<<<NBE, 256, 0, stream>>>(src, dst, bcnt, bcur2, pairs, E);
    k_binB<<<NBUCK, 256, 0, stream>>>(pairs, bcnt, off, idx_sorted, E);

    k_gath<<<(NDST + 3) / 4, 256, 0, stream>>>(
        (const uint32_t*)hd8, (const float4*)agg, off, idx_sorted,
        (ushort4*)Xn, NDST);

    k_gemm<<<NDST / 16, 256, 0, stream>>>(
        (const float4*)H_dst, Xn, WT, bias, out);
}